// Round 9
// baseline (215.876 us; speedup 1.0000x reference)
//
#include <hip/hip_runtime.h>
#include <math.h>

// Problem constants
#define H28 28
#define G784 784
#define BATCH 32
#define NOFF 3025   // 55*55 lattice offsets (|di|,|dj| <= 27)
#define NOFFP 3072  // padded to multiple of 64
#define NKEY 1459   // keys di*di+dj*dj in [0, 1458]
#define TPTS 25
#define KMAX 2
#define NFEAT 50    // KMAX*TPTS
#define OUTF 50
#define NCLS 10

#define NBX 28      // dtm blocks per batch
#define BT 512      // threads per block (8 waves)
#define HS 512      // edge-dedup hash slots (pow2); ne ~ 300 max observed class
#define EMAX 512    // deduped edge capacity
#define MAGIC 0x7C3A9E51u

typedef unsigned long long u64;

// ---------------------------------------------------------------------------
// Compile-time counting-sorted offset table.
// ---------------------------------------------------------------------------
struct OffPair { unsigned ij; float d2; };
struct OffTab  { OffPair e[NOFFP]; };

constexpr double csqrt(double x) {
  double r = x * 0.5 + 1.0;
  for (int i = 0; i < 20; i++) r = 0.5 * (r + x / r);
  return r;
}

constexpr OffTab make_offtab() {
  OffTab t{};
  int start[NKEY] = {};
  for (int i = 0; i < NOFF; i++) {
    int di = i / 55 - 27, dj = i % 55 - 27;
    start[di * di + dj * dj]++;
  }
  int run = 0;
  for (int k = 0; k < NKEY; k++) { int h = start[k]; start[k] = run; run += h; }
  for (int i = 0; i < NOFF; i++) {
    int di = i / 55 - 27, dj = i % 55 - 27;
    int key = di * di + dj * dj;
    int pos = start[key]++;
    float sd = (key == 0) ? 0.0f : (float)(csqrt((double)key) * (224.0 / 27.0));
    t.e[pos].ij = ((unsigned)(di & 0xffff)) | (((unsigned)(dj & 0xffff)) << 16);
    t.e[pos].d2 = sd * sd;
  }
  for (int i = NOFF; i < NOFFP; i++) { t.e[i].ij = 0x00640064u; t.e[i].d2 = 0.f; }
  return t;
}

__device__ constexpr OffTab OFFTAB = make_offtab();

// ---------------------------------------------------------------------------
// wave64 inclusive scan via DPP.
// ---------------------------------------------------------------------------
__device__ __forceinline__ float wave_iscan_f32(float x) {
  int t;
  t = __builtin_amdgcn_update_dpp(0, __float_as_int(x), 0x111, 0xf, 0xf, true);
  x += __int_as_float(t);
  t = __builtin_amdgcn_update_dpp(0, __float_as_int(x), 0x112, 0xf, 0xf, true);
  x += __int_as_float(t);
  t = __builtin_amdgcn_update_dpp(0, __float_as_int(x), 0x114, 0xf, 0xf, true);
  x += __int_as_float(t);
  t = __builtin_amdgcn_update_dpp(0, __float_as_int(x), 0x118, 0xf, 0xf, true);
  x += __int_as_float(t);
  t = __builtin_amdgcn_update_dpp(0, __float_as_int(x), 0x142, 0xa, 0xf, true);
  x += __int_as_float(t);
  t = __builtin_amdgcn_update_dpp(0, __float_as_int(x), 0x143, 0xc, 0xf, true);
  x += __int_as_float(t);
  return x;
}

__device__ __forceinline__ u64 key_of(float v, int p) {
  return (((u64)__float_as_uint(v)) << 10) | (unsigned)p;
}

// ---------------------------------------------------------------------------
// Shared-memory overlays (union keeps every block at ~37.5 KB -> 4 blocks/CU)
// ---------------------------------------------------------------------------
struct SmemDtm {
  float w_s[G784];
  float red[BT / 64];
};
struct SmemPd0 {
  u64   oldkey[G784];
  float val_s[G784];
  int   ptr_s[G784];
  int   parent[G784];
  unsigned claims[G784];
  float deathv[G784];
  int   mlist[G784];
  union {
    struct { u64 hval[HS]; u64 edges[EMAX]; unsigned htag[HS]; } h;
    float xt[BATCH * OUTF];
  } hx;
  float redf[BT / 64];
  float lt1[8][32];
  float lt2[8][32];
  int   mcnt, ecnt;
};
union Smem { SmemDtm d; SmemPd0 p; };

// ---------------------------------------------------------------------------
// Fused kernel. grid = BATCH*NBX + BATCH blocks of BT threads.
//   blk <  896: dtm role for (b=blk/NBX, bx=blk%NBX); release stamp[blk].
//   blk >= 896: pd0 role for b=blk-896; acquire 28 stamps, run pd0+landscape,
//               release dstamp[b]; block b==31 then acquires all dstamps and
//               runs the dense head.
// ---------------------------------------------------------------------------
__global__ __launch_bounds__(BT, 8)
void fused_kernel(const float* __restrict__ x,
                  float* __restrict__ v,
                  float* __restrict__ feats,
                  unsigned* __restrict__ stamp,    // [BATCH*NBX]
                  unsigned* __restrict__ dstamp,   // [BATCH]
                  const float* __restrict__ w_land,
                  const float* __restrict__ b_land,
                  const float* __restrict__ w_fc,
                  const float* __restrict__ b_fc,
                  float* __restrict__ out) {
  __shared__ Smem sm;
  const int blk  = blockIdx.x;
  const int tid  = threadIdx.x;
  const int wave = tid >> 6;
  const int lane = tid & 63;

  if (blk < BATCH * NBX) {
    // ================= DTM role =================
    const int b  = blk / NBX;
    const int bx = blk % NBX;

    float ps = 0.f;
    for (int i = tid; i < G784; i += BT) {
      float wv = x[b * G784 + i];
      sm.d.w_s[i] = wv;
      ps += wv;
    }
    for (int off = 32; off > 0; off >>= 1) ps += __shfl_xor(ps, off);
    if (lane == 0) sm.d.red[wave] = ps;
    __syncthreads();
    float tot = 0.f;
    for (int k = 0; k < BT / 64; k++) tot += sm.d.red[k];
    const float bound = 0.2f * tot;

    const int slot = bx * 8 + wave;
    for (int g = slot; g < G784; g += NBX * 8) {
      const int i1 = g / H28, j1 = g % H28;
      float cw = 0.f, cwd = 0.f;
      float cwp = 0.f, cwdp = 0.f, dk2 = 0.f;
      bool crossed = false;
      int o = lane;
      unsigned ij = OFFTAB.e[o].ij;
      float d2v   = OFFTAB.e[o].d2;
      for (int base = 0; base < NOFFP && !crossed; base += 64) {
        int onext = o + 64;
        if (onext >= NOFFP) onext = o;
        const unsigned ij_n = OFFTAB.e[onext].ij;
        const float    d2_n = OFFTAB.e[onext].d2;
        const int di = (short)(ij & 0xffffu);
        const int dj = (short)(ij >> 16);
        const int i2 = i1 + di, j2 = j1 + dj;
        const bool inb = ((unsigned)i2 < (unsigned)H28) & ((unsigned)j2 < (unsigned)H28);
        const float wv = inb ? sm.d.w_s[i2 * H28 + j2] : 0.f;
        const float wd = wv * d2v;
        const float psw = wave_iscan_f32(wv);
        const float psd = wave_iscan_f32(wd);
        const u64 mask = __ballot(cw + psw >= bound);
        if (mask) {
          const int f = __ffsll((u64)mask) - 1;
          const float psw_f = __shfl(psw, f);
          const float w_f   = __shfl(wv, f);
          const float psd_f = __shfl(psd, f);
          const float wd_f  = __shfl(wd, f);
          dk2  = __shfl(d2v, f);
          cwp  = cw + (psw_f - w_f);
          cwdp = cwd + (psd_f - wd_f);
          crossed = true;
        } else {
          cw  += __int_as_float(__builtin_amdgcn_readlane(__float_as_int(psw), 63));
          cwd += __int_as_float(__builtin_amdgcn_readlane(__float_as_int(psd), 63));
        }
        ij = ij_n; d2v = d2_n; o = onext;
      }
      const float val = (cwdp + (bound - cwp) * dk2) / bound;
      if (lane == 0) v[b * G784 + g] = sqrtf(fmaxf(val, 0.f));
    }

    __syncthreads();
    __threadfence();
    if (tid == 0)
      __hip_atomic_store(&stamp[blk], MAGIC, __ATOMIC_RELEASE,
                         __HIP_MEMORY_SCOPE_AGENT);
    return;
  }

  // ================= PD0 role =================
  const int b = blk - BATCH * NBX;
  if (tid == 0) { sm.p.mcnt = 0; sm.p.ecnt = 0; }
  if (tid < NBX) {
    while (__hip_atomic_load(&stamp[b * NBX + tid], __ATOMIC_ACQUIRE,
                             __HIP_MEMORY_SCOPE_AGENT) != MAGIC)
      __builtin_amdgcn_s_sleep(8);
  }
  __syncthreads();                               // stamps acquired, counters 0

  // --- phase 1: forest from global; minima; hash init ---
  const float* vb = v + b * G784;
  float pm = -1e30f;
  for (int p = tid; p < G784; p += BT) {
    int i = p / H28, j = p % H28;
    float vp = vb[p];
    sm.p.val_s[p] = vp;
    pm = fmaxf(pm, vp);
    u64 bk = key_of(vp, p);
    int best = p;
    if (i > 0)       { int q = p - H28; u64 kq = key_of(vb[q], q); if (kq < bk) { bk = kq; best = q; } }
    if (i < H28 - 1) { int q = p + H28; u64 kq = key_of(vb[q], q); if (kq < bk) { bk = kq; best = q; } }
    if (j > 0)       { int q = p - 1;   u64 kq = key_of(vb[q], q); if (kq < bk) { bk = kq; best = q; } }
    if (j < H28 - 1) { int q = p + 1;   u64 kq = key_of(vb[q], q); if (kq < bk) { bk = kq; best = q; } }
    sm.p.ptr_s[p] = best;
    if (best == p) { int mi = atomicAdd(&sm.p.mcnt, 1); sm.p.mlist[mi] = p; }
  }
  for (int i = tid; i < HS; i += BT) { sm.p.hx.h.htag[i] = 0u; sm.p.hx.h.hval[i] = ~0ULL; }
  for (int off = 32; off > 0; off >>= 1) pm = fmaxf(pm, __shfl_xor(pm, off));
  if (lane == 0) sm.p.redf[wave] = pm;
  __syncthreads();                               // B1

  float vmax = sm.p.redf[0];
  for (int k = 1; k < BT / 64; k++) vmax = fmaxf(vmax, sm.p.redf[k]);
  const int mcnt = sm.p.mcnt;

  // --- phase 2: chase-to-root publish; minima UF init ---
  for (int p = tid; p < G784; p += BT) {
    int xx = sm.p.ptr_s[p];
    int yy = sm.p.ptr_s[xx];
    while (yy != xx) { xx = yy; yy = sm.p.ptr_s[xx]; }
    sm.p.ptr_s[p] = xx;
  }
  for (int i = tid; i < mcnt; i += BT) {
    int m = sm.p.mlist[i];
    sm.p.parent[m] = m;
    sm.p.claims[m] = 0xFFFFFFFFu;
    sm.p.deathv[m] = vmax;
    sm.p.oldkey[m] = key_of(sm.p.val_s[m], m);
  }
  __syncthreads();                               // B2

  // --- phase 3: cross-basin edges -> hash dedup (per-pair min key) ---
  for (int p = tid; p < G784; p += BT) {
    u64 kp = key_of(sm.p.val_s[p], p);
    int i = p / H28, j = p % H28;
    int nbs[4];
    nbs[0] = (i > 0)       ? p - H28 : -1;
    nbs[1] = (i < H28 - 1) ? p + H28 : -1;
    nbs[2] = (j > 0)       ? p - 1   : -1;
    nbs[3] = (j < H28 - 1) ? p + 1   : -1;
    int bp = sm.p.ptr_s[p];
    for (int t = 0; t < 4; t++) {
      int q = nbs[t];
      if (q >= 0) {
        u64 kq = key_of(sm.p.val_s[q], q);
        int bq = sm.p.ptr_s[q];
        if (kq < kp && bq != bp) {
          u64 key = (((u64)__float_as_uint(sm.p.val_s[p])) << 32) |
                    (((u64)(unsigned)p) << 22) |
                    (((u64)(unsigned)t) << 20) |
                    (((u64)(unsigned)bp) << 10) |
                    ((u64)(unsigned)bq);
          unsigned lo = (bp < bq) ? (unsigned)bp : (unsigned)bq;
          unsigned hi = (bp < bq) ? (unsigned)bq : (unsigned)bp;
          unsigned pairid = (lo << 10) | hi;
          unsigned idx = (pairid * 2654435761u) >> 23;   // HS=512
          for (;;) {
            unsigned t0 = atomicCAS(&sm.p.hx.h.htag[idx], 0u, pairid + 1u);
            if (t0 == 0u || t0 == pairid + 1u) {
              atomicMin(&sm.p.hx.h.hval[idx], key); break;
            }
            idx = (idx + 1) & (HS - 1);
          }
        }
      }
    }
  }
  __syncthreads();                               // B3

  // --- phase 4: compact hash -> edges ---
  for (int i = tid; i < HS; i += BT) {
    if (sm.p.hx.h.htag[i]) {
      int e = atomicAdd(&sm.p.ecnt, 1);
      if (e < EMAX) sm.p.hx.h.edges[e] = sm.p.hx.h.hval[i];
    }
  }
  __syncthreads();                               // B4
  const int ne = (sm.p.ecnt < EMAX) ? sm.p.ecnt : EMAX;

  // --- phase 5: rank sort (ne <= 512 == BT; unique keys) ---
  {
    u64 m0 = 0;
    int r0 = 0;
    const bool h0 = (tid < ne);
    if (h0) m0 = sm.p.hx.h.edges[tid];
    for (int j = 0; j < ne; j++) {
      u64 ej = sm.p.hx.h.edges[j];
      r0 += (ej < m0) ? 1 : 0;
    }
    if (h0) sm.p.hx.h.hval[r0] = m0;
  }
  __syncthreads();                               // B5
  const u64* sedges = sm.p.hx.h.hval;

  // --- phase 6: wave0 claim-based Kruskal (sequential-order exact) ---
  if (wave == 0) {
    int merged = 0;
    const int target = mcnt - 1;
    for (int base = 0; base < ne && merged < target; base += 64) {
      const int idx = base + lane;
      bool unresolved = (idx < ne);
      const u64 e = unresolved ? sedges[idx] : 0ULL;
      const int A  = (int)((e >> 10) & 1023u);
      const int Bq = (int)(e & 1023u);
      const float ev = __uint_as_float((unsigned)(e >> 32));
      for (;;) {
        int rA = A, rB = Bq;
        if (unresolved) {
          int xx = A;
          for (;;) { int p1 = sm.p.parent[xx]; if (p1 == xx) break;
                     int p2 = sm.p.parent[p1]; sm.p.parent[xx] = p2; xx = p2; }
          rA = xx;
          xx = Bq;
          for (;;) { int p1 = sm.p.parent[xx]; if (p1 == xx) break;
                     int p2 = sm.p.parent[p1]; sm.p.parent[xx] = p2; xx = p2; }
          rB = xx;
        }
        bool crossing = unresolved && (rA != rB);
        if (unresolved && !crossing) unresolved = false;
        if (__ballot(crossing) == 0ULL) break;
        if (crossing) {
          atomicMin(&sm.p.claims[rA], (unsigned)lane);
          atomicMin(&sm.p.claims[rB], (unsigned)lane);
        }
        __threadfence_block();
        bool win = crossing && sm.p.claims[rA] == (unsigned)lane
                            && sm.p.claims[rB] == (unsigned)lane;
        __threadfence_block();
        if (crossing) { sm.p.claims[rA] = 0xFFFFFFFFu; sm.p.claims[rB] = 0xFFFFFFFFu; }
        if (win) {
          u64 ka = sm.p.oldkey[rA], kb = sm.p.oldkey[rB];
          int big   = (rA < rB) ? rA : rB;      // union by min index
          int small = (big == rA) ? rB : rA;
          sm.p.parent[small] = big;
          u64 okmin = (ka < kb) ? ka : kb;
          u64 okmax = (ka < kb) ? kb : ka;
          sm.p.oldkey[big] = okmin;
          int dying = (int)(okmax & 1023u);
          sm.p.deathv[dying] = ev;
          unresolved = false;
        }
        __threadfence_block();
        merged += (int)__popcll(__ballot(win));
        if (merged >= target) break;
      }
    }
  }
  __syncthreads();                               // B6

  // --- phase 7: landscape partials, 8 waves over minima slices ---
  {
    float ti = (lane < TPTS) ? (float)((double)lane * (100.0 / 24.0)) : 0.f;
    float t1 = 0.f, t2 = 0.f;
    for (int ii = wave; ii < mcnt; ii += 8) {
      int m = sm.p.mlist[ii];
      float tent = fmaxf(fminf(ti - sm.p.val_s[m], sm.p.deathv[m] - ti), 0.f);
      if (tent > t1)      { t2 = t1; t1 = tent; }
      else if (tent > t2) { t2 = tent; }
    }
    if (lane < TPTS) { sm.p.lt1[wave][lane] = t1; sm.p.lt2[wave][lane] = t2; }
  }
  __syncthreads();                               // B7

  if (wave == 0 && lane < TPTS) {
    float t1 = 0.f, t2 = 0.f;
    for (int w = 0; w < 8; w++) {
      float a1 = sm.p.lt1[w][lane], a2 = sm.p.lt2[w][lane];
      float nt1 = fmaxf(t1, a1);
      float nt2 = fmaxf(fminf(t1, a1), fmaxf(t2, a2));
      t1 = nt1; t2 = nt2;
    }
    feats[b * NFEAT + lane]        = t1;
    feats[b * NFEAT + TPTS + lane] = t2;
  }

  __threadfence();
  __syncthreads();
  if (tid == 0)
    __hip_atomic_store(&dstamp[b], MAGIC, __ATOMIC_RELEASE,
                       __HIP_MEMORY_SCOPE_AGENT);

  // ---- head: fixed block b == BATCH-1 waits for all, then computes ----
  if (b != BATCH - 1) return;
  if (tid < BATCH) {
    while (__hip_atomic_load(&dstamp[tid], __ATOMIC_ACQUIRE,
                             __HIP_MEMORY_SCOPE_AGENT) != MAGIC)
      __builtin_amdgcn_s_sleep(8);
  }
  __syncthreads();

  for (int idx = tid; idx < BATCH * OUTF; idx += BT) {
    int bb = idx / OUTF, ff = idx % OUTF;
    float acc = b_land[ff];
    const float* wr = w_land + ff * NFEAT;
    const float* fr = feats + bb * NFEAT;
    for (int j = 0; j < NFEAT; j++) acc += fr[j] * wr[j];
    sm.p.hx.xt[idx] = acc;
  }
  __syncthreads();
  if (tid < OUTF) {
    float s = 0.f;
    for (int bb = 0; bb < BATCH; bb++) s += fabsf(sm.p.hx.xt[bb * OUTF + tid]);
    out[BATCH * NCLS + tid] = s;
  }
  for (int idx = tid; idx < BATCH * NCLS; idx += BT) {
    int bb = idx / NCLS, cc = idx % NCLS;
    float acc = b_fc[cc];
    const float* wr = w_fc + cc * OUTF;
    const float* xr = sm.p.hx.xt + bb * OUTF;
    for (int ff = 0; ff < OUTF; ff++) acc += fmaxf(xr[ff], 0.f) * wr[ff];
    out[bb * NCLS + cc] = acc;
  }
}

// ---------------------------------------------------------------------------
extern "C" void kernel_launch(void* const* d_in, const int* in_sizes, int n_in,
                              void* d_out, int out_size, void* d_ws, size_t ws_size,
                              hipStream_t stream) {
  (void)in_sizes; (void)n_in; (void)out_size; (void)ws_size;
  const float* x      = (const float*)d_in[0];   // [32,1,28,28]
  const float* w_land = (const float*)d_in[1];   // [50,50]
  const float* b_land = (const float*)d_in[2];   // [50]
  const float* w_fc   = (const float*)d_in[3];   // [10,50]
  const float* b_fc   = (const float*)d_in[4];   // [10]
  float* out    = (float*)d_out;                 // [32*10] out then [50] signal
  float* v      = (float*)d_ws;                  // [32*784]
  float* feats  = v + BATCH * G784;              // [32*50]
  unsigned* stp = (unsigned*)(feats + BATCH * NFEAT);  // [BATCH*NBX]
  unsigned* dst = stp + BATCH * NBX;                   // [BATCH]

  fused_kernel<<<BATCH * NBX + BATCH, BT, 0, stream>>>(
      x, v, feats, stp, dst, w_land, b_land, w_fc, b_fc, out);
}